// Round 9
// baseline (91.237 us; speedup 1.0000x reference)
//
#include <hip/hip_runtime.h>

// GaussianBlur 3x3 sigma=0 -> separable [0.25,0.5,0.25], BORDER_REFLECT_101.
// f32 [64,3,512,512]. LDS-staged stencil: each 256-thread block (4 waves)
// owns a 16-row strip of one plane; 18 rows (strip + halo) are staged into
// LDS once via async global_load_lds (width 16) -> fabric-level read traffic
// drops from 1.5x to 1.125x of input (FETCH_SIZE can't see this: L3 serves
// the re-reads, but the fabric pays for them). Each wave then reads its 6
// rows from LDS into registers (12 ds_read_b128) and computes 4 output rows
// exactly as the R4 structure: vertical blur with register reuse, horizontal
// neighbors via lane shuffles, nontemporal stores.

#define HH 512
#define WW 512
#define STRIP 16            // output rows per block
#define SROWS (STRIP + 2)   // staged rows incl. halo

typedef float f4 __attribute__((ext_vector_type(4)));

#define VBLUR(d, m, c, pq)                         \
    d.x = 0.25f * (m.x + pq.x) + 0.5f * c.x;       \
    d.y = 0.25f * (m.y + pq.y) + 0.5f * c.y;       \
    d.z = 0.25f * (m.z + pq.z) + 0.5f * c.z;       \
    d.w = 0.25f * (m.w + pq.w) + 0.5f * c.w;

#define HBLUR(oa, ob, ua, ub, l, r)                \
    oa.x = 0.25f * (l    + ua.y) + 0.5f * ua.x;    \
    oa.y = 0.25f * (ua.x + ua.z) + 0.5f * ua.y;    \
    oa.z = 0.25f * (ua.y + ua.w) + 0.5f * ua.z;    \
    oa.w = 0.25f * (ua.z + ub.x) + 0.5f * ua.w;    \
    ob.x = 0.25f * (ua.w + ub.y) + 0.5f * ub.x;    \
    ob.y = 0.25f * (ub.x + ub.z) + 0.5f * ub.y;    \
    ob.z = 0.25f * (ub.y + ub.w) + 0.5f * ub.z;    \
    ob.w = 0.25f * (ub.z + r   ) + 0.5f * ub.w;

#define ROW_FINISH(ua, ub, S)                                        \
    {                                                                \
        float l = __shfl_up(ub.w, 1);                                \
        float r = __shfl_down(ua.x, 1);                              \
        if (lane == 0)  l = ua.y;                                    \
        if (lane == 63) r = ub.z;                                    \
        f4 oa, ob;                                                   \
        HBLUR(oa, ob, ua, ub, l, r)                                  \
        __builtin_nontemporal_store(oa, (S));                        \
        __builtin_nontemporal_store(ob, (S) + 1);                    \
    }

__global__ __launch_bounds__(256) void gauss3_kernel(const float* __restrict__ in,
                                                     float* __restrict__ out) {
    __shared__ float lds[SROWS * WW];   // 36864 B

    int bid   = blockIdx.x;
    int plane = bid >> 5;          // 32 strips per (b,c) plane
    int strip = bid & 31;
    int h0    = strip << 4;        // first output row of this strip
    int row_start = (h0 == 0) ? 0 : h0 - 1;   // first staged global row

    int tid  = threadIdx.x;
    int lane = tid & 63;
    int wv   = tid >> 6;

    const float* p = in  + (size_t)plane * (HH * WW);
    float*       q = out + (size_t)plane * (HH * WW);

    // ---- stage SROWS rows into LDS (linear), 9 async 4KB chunks ----
    // chunk i: floats [i*1024, i*1024+1024), thread t covers 4 floats
#pragma unroll
    for (int i = 0; i < (SROWS * WW) / 1024; ++i) {
        int o    = i * 1024 + tid * 4;        // float offset within strip
        int rrel = o >> 9;                    // row within staged window
        int col  = o & (WW - 1);
        int grow = row_start + rrel;
        if (grow > HH - 1) grow = HH - 1;     // clamp (last strip only)
        const float* src = p + (size_t)grow * WW + col;
        __builtin_amdgcn_global_load_lds(
            (const __attribute__((address_space(1))) void*)src,
            (__attribute__((address_space(3))) void*)(lds + o),
            16, 0, 0);
    }
    __syncthreads();

    // ---- compute: wave wv owns output rows g0..g0+3 ----
    int g0 = h0 + (wv << 2);
    int gm = (g0 == 0)       ? 1      : g0 - 1;   // reflect-101
    int gp = (g0 + 4 == HH)  ? HH - 2 : g0 + 4;   // reflect-101

    int w0 = lane << 3;   // 8 px per lane
    const f4* Lm = (const f4*)(lds + (gm         - row_start) * WW + w0);
    const f4* L0 = (const f4*)(lds + (g0         - row_start) * WW + w0);
    const f4* L1 = (const f4*)(lds + (g0 + 1     - row_start) * WW + w0);
    const f4* L2 = (const f4*)(lds + (g0 + 2     - row_start) * WW + w0);
    const f4* L3 = (const f4*)(lds + (g0 + 3     - row_start) * WW + w0);
    const f4* Lp = (const f4*)(lds + (gp         - row_start) * WW + w0);

    f4 ama = Lm[0], amb = Lm[1];
    f4 a0a = L0[0], a0b = L0[1];
    f4 a1a = L1[0], a1b = L1[1];
    f4 a2a = L2[0], a2b = L2[1];
    f4 a3a = L3[0], a3b = L3[1];
    f4 apa = Lp[0], apb = Lp[1];

    float* qb = q + w0;
    f4 ua, ub;
    VBLUR(ua, ama, a0a, a1a)  VBLUR(ub, amb, a0b, a1b)
    ROW_FINISH(ua, ub, (f4*)(qb + (size_t)g0       * WW))
    VBLUR(ua, a0a, a1a, a2a)  VBLUR(ub, a0b, a1b, a2b)
    ROW_FINISH(ua, ub, (f4*)(qb + (size_t)(g0 + 1) * WW))
    VBLUR(ua, a1a, a2a, a3a)  VBLUR(ub, a1b, a2b, a3b)
    ROW_FINISH(ua, ub, (f4*)(qb + (size_t)(g0 + 2) * WW))
    VBLUR(ua, a2a, a3a, apa)  VBLUR(ub, a2b, a3b, apb)
    ROW_FINISH(ua, ub, (f4*)(qb + (size_t)(g0 + 3) * WW))
}

extern "C" void kernel_launch(void* const* d_in, const int* in_sizes, int n_in,
                              void* d_out, int out_size, void* d_ws, size_t ws_size,
                              hipStream_t stream) {
    const float* x   = (const float*)d_in[0];
    float*       out = (float*)d_out;

    int n      = in_sizes[0];          // 64*3*512*512
    int planes = n / (HH * WW);        // 192
    int blocks = planes * (HH / STRIP);  // 192 * 32 = 6144
    gauss3_kernel<<<blocks, 256, 0, stream>>>(x, out);
}

// Round 10
// 65.959 us; speedup vs baseline: 1.3832x; 1.3832x over previous
//
#include <hip/hip_runtime.h>

// GaussianBlur 3x3 sigma=0 -> separable [0.25,0.5,0.25], BORDER_REFLECT_101.
// f32 [64,3,512,512]. One wave per 4-row quad (R4 structure, best so far).
// NEW: dense access pattern -- lane l owns floats [4l,4l+4) and
// [256+4l,256+4l+4) of each row (two half-row streams), so EVERY b128
// load/store instruction is a fully-contiguous 1 KiB wave access. This
// removes the half-density 2KiB spans of the previous layout, whose
// partial-line NT write-back amplified WRITE_SIZE 196.6->215-226 MB.
// Cross-half seam resolved with two broadcast shuffles per row.

#define HH 512
#define WW 512

typedef float f4 __attribute__((ext_vector_type(4)));

#define VBLUR(d, m, c, pq)                         \
    d.x = 0.25f * (m.x + pq.x) + 0.5f * c.x;       \
    d.y = 0.25f * (m.y + pq.y) + 0.5f * c.y;       \
    d.z = 0.25f * (m.z + pq.z) + 0.5f * c.z;       \
    d.w = 0.25f * (m.w + pq.w) + 0.5f * c.w;

// horizontal blur of one f4 with scalar left/right neighbors
#define HBLUR1(o, u, l, r)                         \
    o.x = 0.25f * (l   + u.y) + 0.5f * u.x;        \
    o.y = 0.25f * (u.x + u.z) + 0.5f * u.y;        \
    o.z = 0.25f * (u.y + u.w) + 0.5f * u.z;        \
    o.w = 0.25f * (u.z + r  ) + 0.5f * u.w;

// vertical blur both halves, resolve seam + edges, horizontal blur, NT store
#define ROW(ma, mb, ca, cb, pa, pb, h)                               \
    {                                                                \
        f4 uA, uB;                                                   \
        VBLUR(uA, ma, ca, pa)                                        \
        VBLUR(uB, mb, cb, pb)                                        \
        float lA = __shfl_up(uA.w, 1);                               \
        float rA = __shfl_down(uA.x, 1);                             \
        float lB = __shfl_up(uB.w, 1);                               \
        float rB = __shfl_down(uB.x, 1);                             \
        float aw63 = __shfl(uA.w, 63);   /* elem 255 */              \
        float bx0  = __shfl(uB.x, 0);    /* elem 256 */              \
        if (lane == 0)  { lA = uA.y; lB = aw63; }  /* reflect -1->1 */\
        if (lane == 63) { rA = bx0;  rB = uB.z; }  /* reflect 512->510 */\
        f4 oA, oB;                                                   \
        HBLUR1(oA, uA, lA, rA)                                       \
        HBLUR1(oB, uB, lB, rB)                                       \
        f4* S = (f4*)(qb + (size_t)(h) * WW);                        \
        __builtin_nontemporal_store(oA, S);                          \
        __builtin_nontemporal_store(oB, S + 64);  /* +256 floats */  \
    }

__global__ __launch_bounds__(256) void gauss3_kernel(const float* __restrict__ in,
                                                     float* __restrict__ out) {
    int wid  = (blockIdx.x * 256 + threadIdx.x) >> 6;  // global wave id
    int lane = threadIdx.x & 63;

    int quad  = wid & 127;   // 128 row-quads per (b,c) plane
    int plane = wid >> 7;

    int h0 = quad << 2;                           // output rows h0 .. h0+3
    int hm = (h0 == 0)       ? 1      : h0 - 1;   // reflect-101
    int hp = (h0 + 4 == HH)  ? HH - 2 : h0 + 4;   // reflect-101

    const float* p = in  + (size_t)plane * (HH * WW);
    float*       q = out + (size_t)plane * (HH * WW);

    const float* pb = p + (lane << 2);   // lane's dense 16B slot, half A
    float*       qb = q + (lane << 2);

    const f4* Lm = (const f4*)(pb + (size_t)hm       * WW);
    const f4* L0 = (const f4*)(pb + (size_t)h0       * WW);
    const f4* L1 = (const f4*)(pb + (size_t)(h0 + 1) * WW);
    const f4* L2 = (const f4*)(pb + (size_t)(h0 + 2) * WW);
    const f4* L3 = (const f4*)(pb + (size_t)(h0 + 3) * WW);
    const f4* Lp = (const f4*)(pb + (size_t)hp       * WW);

    // 12 wide loads, each a dense 1 KiB wave access (half B at +64 f4)
    f4 ama = Lm[0], amb = Lm[64];
    f4 a0a = L0[0], a0b = L0[64];
    f4 a1a = L1[0], a1b = L1[64];
    f4 a2a = L2[0], a2b = L2[64];
    f4 a3a = L3[0], a3b = L3[64];
    f4 apa = Lp[0], apb = Lp[64];

    ROW(ama, amb, a0a, a0b, a1a, a1b, h0)
    ROW(a0a, a0b, a1a, a1b, a2a, a2b, h0 + 1)
    ROW(a1a, a1b, a2a, a2b, a3a, a3b, h0 + 2)
    ROW(a2a, a2b, a3a, a3b, apa, apb, h0 + 3)
}

extern "C" void kernel_launch(void* const* d_in, const int* in_sizes, int n_in,
                              void* d_out, int out_size, void* d_ws, size_t ws_size,
                              hipStream_t stream) {
    const float* x   = (const float*)d_in[0];
    float*       out = (float*)d_out;

    int n      = in_sizes[0];          // 64*3*512*512
    int planes = n / (HH * WW);        // 192
    int waves  = planes * (HH / 4);    // one wave per row-quad: 24576
    int blocks = waves / 4;            // 4 waves per 256-thread block: 6144

    gauss3_kernel<<<blocks, 256, 0, stream>>>(x, out);
}